// Round 12
// baseline (48.919 us; speedup 1.0000x reference)
//
#include <hip/hip_runtime.h>

// DynamicMaskHead, barrier-free rolling-window kernel. One thread owns one
// input COLUMN of one instance and walks TR rows: computes logit(r,c) via the
// dynamic MLP, keeps a 3-row logit window in registers, gets x-neighbors via
// wave shuffles (no LDS tile, no __syncthreads after the params load -- hipcc
// drains vmcnt(0) at every barrier, which serialized all previous phase-
// structured versions at ~31-34us = serial sum of compute + stores).
// Stores are emitted every iteration -> store queue continuously fed.
// Wave covers 64 cols, emits 62 (lanes 0,63 are halo); 3 waves cover W=152.
// Shapes fixed by harness: N=2, Cin=8, H=100, W=152, n_inst=100, stride=8.

#define CIN 8
#define HH 100
#define WW 152
#define HWSZ (HH * WW)
#define NI 100
#define OH (HH * 4)
#define OW (WW * 4)
#define TR 10                              // emitted rows per block (HH%TR==0)
#define BLOCK 192                          // 3 waves

__device__ __forceinline__ float fast_rcp(float x) {
    return __builtin_amdgcn_rcpf(x);       // v_rcp_f32, ~1 ulp
}

__device__ __forceinline__ float fast_mish(float x) {
    // mish(x) = x * n/(n+2), n = e(e+2), e = exp(x). Clamp only the exp arg:
    // for x>20, n/(n+2)==1 in fp32 -> formula stays exact, branchless.
    float e = __expf(fminf(x, 20.f));
    float n = e * (e + 2.f);
    return x * n * fast_rcp(n + 2.f);
}

__device__ __forceinline__ float fast_sigmoid(float z) {
    return fast_rcp(1.f + __expf(-z));
}

__global__ void __launch_bounds__(BLOCK)
fused_mask_head_kernel(const float* __restrict__ mask_feats,
                       const float* __restrict__ params,
                       const float* __restrict__ inst_locs,
                       const int* __restrict__ im_inds,
                       const int* __restrict__ fpn_levels,
                       const int* __restrict__ stride_ptr,
                       float* __restrict__ out) {
    __shared__ float prm[169];
    const int inst = blockIdx.y;
    const int r0 = blockIdx.x * TR;
    const int t = threadIdx.x;
    if (t < 169) prm[t] = params[inst * 169 + t];
    __syncthreads();                        // the only barrier in the kernel

    const int wave = t >> 6;
    const int lane = t & 63;
    const int c = wave * 62 + lane - 1;     // center column (may be OOB on halo lanes)
    const int colc = min(max(c, 0), WW - 1);
    const bool emit_ok = (lane >= 1) && (lane <= 62) && (c >= 0) && (c < WW);

    // block-uniform instance scalars
    const int stride = stride_ptr[0];
    const float half = (float)(stride / 2);
    const float soi_tab[5] = {64.f, 128.f, 256.f, 512.f, 1024.f};
    const float inv_soi = 1.f / soi_tab[fpn_levels[inst]];
    const float lx = inst_locs[inst * 2 + 0];
    const float ly = inst_locs[inst * 2 + 1];
    const float xrel = (lx - (float)(colc * stride) - half) * inv_soi;  // col term, fixed
    const float* fcol = mask_feats + (size_t)im_inds[inst] * CIN * HWSZ + colc;
    float* const obase = out + (size_t)inst * (OH * OW);

    // rolling 3-row logit window, each row as (left, center, right)
    float pl = 0.f, pm = 0.f, prr = 0.f;
    float clft = 0.f, cm = 0.f, crt = 0.f;
    float nl = 0.f, nm = 0.f, nr = 0.f;

    // feature prefetch for first row
    float f[CIN], fn[CIN];
    {
        const int rr = min(max(r0 - 1, 0), HH - 1);
        const float* fr = fcol + rr * WW;
#pragma unroll
        for (int ch = 0; ch < CIN; ++ch) f[ch] = fr[(size_t)ch * HWSZ];
    }

    for (int i = 0; i < TR + 2; ++i) {
        const int rU = r0 + i - 1;                       // unclamped row being computed
        const int rr = min(max(rU, 0), HH - 1);

        // prefetch next row's features (hidden under this row's MLP)
        if (i < TR + 1) {
            const int rn = min(max(rU + 1, 0), HH - 1);
            const float* fr = fcol + rn * WW;
#pragma unroll
            for (int ch = 0; ch < CIN; ++ch) fn[ch] = fr[(size_t)ch * HWSZ];
        }

        // ---- MLP for (rr, colc): 10 -> 8 -> 8 -> 1, mish ----
        const float relY = (ly - (float)(rr * stride) - half) * inv_soi;
        float h1[8];
#pragma unroll
        for (int o = 0; o < 8; ++o) {
            float acc = fmaf(prm[o * 10 + 0], xrel, fmaf(prm[o * 10 + 1], relY, prm[152 + o]));
#pragma unroll
            for (int ch = 0; ch < CIN; ++ch) acc = fmaf(prm[o * 10 + 2 + ch], f[ch], acc);
            h1[o] = fast_mish(acc);
        }
        float L = prm[168];
#pragma unroll
        for (int o = 0; o < 8; ++o) {
            float acc = prm[160 + o];
#pragma unroll
            for (int ii = 0; ii < 8; ++ii) acc = fmaf(prm[80 + o * 8 + ii], h1[ii], acc);
            L = fmaf(prm[144 + o], fast_mish(acc), L);
        }

        // neighbors via wave shuffle (halo lanes 0/63 never emit)
        const float Ll = __shfl_up(L, 1);
        const float Lr = __shfl_down(L, 1);

        // shift window
        pl = clft; pm = cm; prr = crt;
        clft = nl;  cm = nm;  crt = nr;
        nl = Ll;  nm = L;   nr = Lr;

        // ---- emit 4x4 output block for rg = rU-1 once window is full ----
        if (i >= 2 && emit_ok) {
            const int rg = rU - 1;                       // in [r0, r0+TR-1]
            // horizontal interp per window row: x-samples k=0..3
            // k0=.5(L+C) k1=.25L+.75C k2=C k3=.75C+.25R
            float h0s[4], h1s[4], h2s[4];
            h0s[0] = 0.5f * (pl + pm);  h0s[1] = fmaf(0.25f, pl, 0.75f * pm);  h0s[2] = pm; h0s[3] = fmaf(0.25f, prr, 0.75f * pm);
            h1s[0] = 0.5f * (clft + cm); h1s[1] = fmaf(0.25f, clft, 0.75f * cm); h1s[2] = cm; h1s[3] = fmaf(0.25f, crt, 0.75f * cm);
            h2s[0] = 0.5f * (nl + nm);  h2s[1] = fmaf(0.25f, nl, 0.75f * nm);  h2s[2] = nm; h2s[3] = fmaf(0.25f, nr, 0.75f * nm);

            float* O = obase + (size_t)(4 * rg) * OW + 4 * c;
            float4 row;
            // k=0: .5 prev + .5 cur
            row.x = fast_sigmoid(0.5f * (h0s[0] + h1s[0]));
            row.y = fast_sigmoid(0.5f * (h0s[1] + h1s[1]));
            row.z = fast_sigmoid(0.5f * (h0s[2] + h1s[2]));
            row.w = fast_sigmoid(0.5f * (h0s[3] + h1s[3]));
            *reinterpret_cast<float4*>(O) = row;
            // k=1: .25 prev + .75 cur
            row.x = fast_sigmoid(fmaf(0.25f, h0s[0], 0.75f * h1s[0]));
            row.y = fast_sigmoid(fmaf(0.25f, h0s[1], 0.75f * h1s[1]));
            row.z = fast_sigmoid(fmaf(0.25f, h0s[2], 0.75f * h1s[2]));
            row.w = fast_sigmoid(fmaf(0.25f, h0s[3], 0.75f * h1s[3]));
            *reinterpret_cast<float4*>(O + OW) = row;
            // k=2: cur
            row.x = fast_sigmoid(h1s[0]);
            row.y = fast_sigmoid(h1s[1]);
            row.z = fast_sigmoid(h1s[2]);
            row.w = fast_sigmoid(h1s[3]);
            *reinterpret_cast<float4*>(O + 2 * OW) = row;
            // k=3: .75 cur + .25 next
            row.x = fast_sigmoid(fmaf(0.25f, h2s[0], 0.75f * h1s[0]));
            row.y = fast_sigmoid(fmaf(0.25f, h2s[1], 0.75f * h1s[1]));
            row.z = fast_sigmoid(fmaf(0.25f, h2s[2], 0.75f * h1s[2]));
            row.w = fast_sigmoid(fmaf(0.25f, h2s[3], 0.75f * h1s[3]));
            *reinterpret_cast<float4*>(O + 3 * OW) = row;
        }

        // rotate prefetched features in
#pragma unroll
        for (int ch = 0; ch < CIN; ++ch) f[ch] = fn[ch];
    }
}

extern "C" void kernel_launch(void* const* d_in, const int* in_sizes, int n_in,
                              void* d_out, int out_size, void* d_ws, size_t ws_size,
                              hipStream_t stream) {
    const float* mask_feats = (const float*)d_in[0];
    const float* params     = (const float*)d_in[1];
    const float* inst_locs  = (const float*)d_in[2];
    const int*   im_inds    = (const int*)d_in[3];
    const int*   fpn_levels = (const int*)d_in[4];
    const int*   stride_ptr = (const int*)d_in[5];
    float* out = (float*)d_out;

    dim3 block(BLOCK);
    dim3 grid(HH / TR, NI);                // 10 x 100 = 1000 blocks
    fused_mask_head_kernel<<<grid, block, 0, stream>>>(
        mask_feats, params, inst_locs, im_inds, fpn_levels, stride_ptr, out);
}

// Round 13
// 30.894 us; speedup vs baseline: 1.5834x; 1.5834x over previous
//
#include <hip/hip_runtime.h>

// DynamicMaskHead, fused: per-instance dynamic MLP + 4x aligned bilinear +
// sigmoid in ONE kernel. Block = (instance, 10-row chunk), 512 threads,
// __launch_bounds__(512,2) (=128 VGPR cap, 2 blocks/CU).
// R13: weights are read DIRECTLY from global at block-uniform addresses
// (compiler scalarizes to s_load -> SGPR operands) instead of an LDS prm[]
// buffer -- removes ~8us of wave-uniform ds_read traffic from the per-CU LDS
// pipe (R12's per-pixel LDS weight reads cost +18us; R8 counters pin total
// VALU work at ~22us). LDS now holds only the logit tile.
// MLP body stays straight-line one-quad-per-thread (loop-wrapping spills: R8).
// Shapes fixed by harness: N=2, Cin=8, H=100, W=152, n_inst=100, stride=8.

#define CIN 8
#define HH 100
#define WW 152
#define HWSZ (HH * WW)
#define NI 100
#define OH (HH * 4)
#define OW (WW * 4)
#define TROWS 10                           // input rows per block (HH%TROWS==0)
#define LROWS (TROWS + 2)                  // + halo
#define QPR (WW / 4)                       // 38 quads per row
#define NQUADS (LROWS * QPR)               // 456 <= 512: one quad per thread
#define UITEMS (TROWS * WW)                // 1520 upsample work items
#define BLOCK 512

__device__ __forceinline__ float fast_rcp(float x) {
    return __builtin_amdgcn_rcpf(x);       // v_rcp_f32, ~1 ulp
}

__device__ __forceinline__ float fast_mish(float x) {
    // mish(x) = x * n/(n+2), n = e(e+2), e = exp(x). For x>20, n/(n+2)==1 in
    // fp32, so clamping only the exp argument keeps it exact and branchless.
    float e = __expf(fminf(x, 20.f));
    float n = e * (e + 2.f);
    return x * n * fast_rcp(n + 2.f);
}

__device__ __forceinline__ float fast_sigmoid(float z) {
    return fast_rcp(1.f + __expf(-z));
}

__global__ void __launch_bounds__(BLOCK, 2)
fused_mask_head_kernel(const float* __restrict__ mask_feats,
                       const float* __restrict__ params,
                       const float* __restrict__ inst_locs,
                       const int* __restrict__ im_inds,
                       const int* __restrict__ fpn_levels,
                       const int* __restrict__ stride_ptr,
                       float* __restrict__ out) {
    __shared__ float tile[LROWS][WW];      // logit tile (rows r0-1 .. r0+TROWS, clamped)

    const int inst = blockIdx.y;
    const int r0 = blockIdx.x * TROWS;     // first output-relevant input row
    const int t = threadIdx.x;

    // block-uniform weight pointer: all reads below are at uniform addresses
    // -> scalar loads, SGPR operands, zero LDS traffic.
    const float* __restrict__ P = params + inst * 169;

    // block-uniform instance scalars
    const int stride = stride_ptr[0];
    const float half = (float)(stride / 2);
    const float soi_tab[5] = {64.f, 128.f, 256.f, 512.f, 1024.f};
    const float inv_soi = 1.f / soi_tab[fpn_levels[inst]];
    const float lx = inst_locs[inst * 2 + 0];
    const float ly = inst_locs[inst * 2 + 1];
    const float dx = -(float)stride * inv_soi;   // per-pixel x step
    const float* fbase = mask_feats + (size_t)im_inds[inst] * CIN * HWSZ;

    // ------------- MLP phase: one 4-px quad per thread, straight-line -------------
    if (t < NQUADS) {
        const int lr  = t / QPR;           // local row 0..11
        const int qc  = t - lr * QPR;
        const int col = qc * 4;
        const int gr  = min(max(r0 + lr - 1, 0), HH - 1);   // clamped global row

        const float relY = (ly - (float)(gr * stride) - half) * inv_soi;
        const float x0b  = (lx - (float)(col * stride) - half) * inv_soi;

        const float* fb = fbase + gr * WW + col;
        float4 f[CIN];
#pragma unroll
        for (int c = 0; c < CIN; ++c)
            f[c] = *reinterpret_cast<const float4*>(fb + (size_t)c * HWSZ);
#define FEAT(c, j) ((&f[c].x)[(j)])

        // layer 1: 10 -> 8, mish (w1[o][i]=P[o*10+i], b1=P[152+o])
        float h1[8][4];
#pragma unroll
        for (int o = 0; o < 8; ++o) {
            float w[10];
#pragma unroll
            for (int i = 0; i < 10; ++i) w[i] = P[o * 10 + i];
            const float b = P[152 + o];
            const float rowterm = fmaf(w[1], relY, b);   // uniform across j
#pragma unroll
            for (int j = 0; j < 4; ++j) {
                float acc = fmaf(w[0], x0b + (float)j * dx, rowterm);
#pragma unroll
                for (int c = 0; c < CIN; ++c) acc = fmaf(w[2 + c], FEAT(c, j), acc);
                h1[o][j] = fast_mish(acc);
            }
        }
        // layers 2+3 fused: logit[j] = b3 + sum_o w3[o]*mish(w2[o]·h1[:,j]+b2[o])
        float lo[4];
        const float b3 = P[168];
#pragma unroll
        for (int j = 0; j < 4; ++j) lo[j] = b3;
#pragma unroll
        for (int o = 0; o < 8; ++o) {
            float w[8];
#pragma unroll
            for (int i = 0; i < 8; ++i) w[i] = P[80 + o * 8 + i];
            const float b2 = P[160 + o];
            const float w3 = P[144 + o];
#pragma unroll
            for (int j = 0; j < 4; ++j) {
                float acc = b2;
#pragma unroll
                for (int i = 0; i < 8; ++i) acc = fmaf(w[i], h1[i][j], acc);
                lo[j] = fmaf(w3, fast_mish(acc), lo[j]);
            }
        }
        *reinterpret_cast<float4*>(&tile[lr][col]) = make_float4(lo[0], lo[1], lo[2], lo[3]);
#undef FEAT
    }
    __syncthreads();

    // ------------- upsample phase: 1520 4x4 blocks, from LDS tile -------------
    // Output row Y=4r+k weights (coord max(Y-2,0)/4, clamped):
    //   k=0: .5 prev + .5 cur | k=1: .25 prev + .75 cur | k=2: cur | k=3: .75 cur + .25 next
    for (int b = t; b < UITEMS; b += BLOCK) {
        const int rg = b / WW;             // output row group 0..TROWS-1
        const int cg = b - rg * WW;        // input col = output col group
        const int lr = rg + 1;             // center row in tile
        const int gm1 = max(cg - 1, 0), gp1 = min(cg + 1, WW - 1);

        const float v00 = tile[lr - 1][gm1], v01 = tile[lr - 1][cg], v02 = tile[lr - 1][gp1];
        const float v10 = tile[lr    ][gm1], v11 = tile[lr    ][cg], v12 = tile[lr    ][gp1];
        const float v20 = tile[lr + 1][gm1], v21 = tile[lr + 1][cg], v22 = tile[lr + 1][gp1];

        float h0[4], h1[4], h2[4];
        h0[0] = 0.5f * (v00 + v01); h0[1] = fmaf(0.25f, v00, 0.75f * v01); h0[2] = v01; h0[3] = fmaf(0.25f, v02, 0.75f * v01);
        h1[0] = 0.5f * (v10 + v11); h1[1] = fmaf(0.25f, v10, 0.75f * v11); h1[2] = v11; h1[3] = fmaf(0.25f, v12, 0.75f * v11);
        h2[0] = 0.5f * (v20 + v21); h2[1] = fmaf(0.25f, v20, 0.75f * v21); h2[2] = v21; h2[3] = fmaf(0.25f, v22, 0.75f * v21);

        float* O = out + (size_t)inst * (OH * OW) + (size_t)(4 * (r0 + rg)) * OW + 4 * cg;
        float4 row;
        row.x = fast_sigmoid(0.5f * (h0[0] + h1[0]));
        row.y = fast_sigmoid(0.5f * (h0[1] + h1[1]));
        row.z = fast_sigmoid(0.5f * (h0[2] + h1[2]));
        row.w = fast_sigmoid(0.5f * (h0[3] + h1[3]));
        *reinterpret_cast<float4*>(O) = row;
        row.x = fast_sigmoid(fmaf(0.25f, h0[0], 0.75f * h1[0]));
        row.y = fast_sigmoid(fmaf(0.25f, h0[1], 0.75f * h1[1]));
        row.z = fast_sigmoid(fmaf(0.25f, h0[2], 0.75f * h1[2]));
        row.w = fast_sigmoid(fmaf(0.25f, h0[3], 0.75f * h1[3]));
        *reinterpret_cast<float4*>(O + OW) = row;
        row.x = fast_sigmoid(h1[0]);
        row.y = fast_sigmoid(h1[1]);
        row.z = fast_sigmoid(h1[2]);
        row.w = fast_sigmoid(h1[3]);
        *reinterpret_cast<float4*>(O + 2 * OW) = row;
        row.x = fast_sigmoid(fmaf(0.25f, h2[0], 0.75f * h1[0]));
        row.y = fast_sigmoid(fmaf(0.25f, h2[1], 0.75f * h1[1]));
        row.z = fast_sigmoid(fmaf(0.25f, h2[2], 0.75f * h1[2]));
        row.w = fast_sigmoid(fmaf(0.25f, h2[3], 0.75f * h1[3]));
        *reinterpret_cast<float4*>(O + 3 * OW) = row;
    }
}

extern "C" void kernel_launch(void* const* d_in, const int* in_sizes, int n_in,
                              void* d_out, int out_size, void* d_ws, size_t ws_size,
                              hipStream_t stream) {
    const float* mask_feats = (const float*)d_in[0];
    const float* params     = (const float*)d_in[1];
    const float* inst_locs  = (const float*)d_in[2];
    const int*   im_inds    = (const int*)d_in[3];
    const int*   fpn_levels = (const int*)d_in[4];
    const int*   stride_ptr = (const int*)d_in[5];
    float* out = (float*)d_out;

    dim3 block(BLOCK);
    dim3 grid(HH / TROWS, NI);             // 10 x 100 = 1000 blocks
    fused_mask_head_kernel<<<grid, block, 0, stream>>>(
        mask_feats, params, inst_locs, im_inds, fpn_levels, stride_ptr, out);
}